// Round 16
// baseline (86.045 us; speedup 1.0000x reference)
//
#include <hip/hip_runtime.h>
#include <hip/hip_bf16.h>

#define BLK 256
#define SPLITS 24                 // scan splits (grid.x)
#define FPS 136                   // frags per split (divisible by 4)
#define FRTOT (SPLITS * FPS)      // 3264 B-fragments (16 scans each)
#define NSLOT (FRTOT * 16)        // 52224 scan slots (>= N, padded w/ sentinel)
#define THRESH 0.1f
#define KEY_MAX 0xFFFFFFFFu
#define ONE_BF ((unsigned short)0x3F80)  // bf16(1.0)

typedef __attribute__((ext_vector_type(8))) short short8;
typedef __attribute__((ext_vector_type(4))) float floatx4;

__device__ __forceinline__ unsigned short f2bf(float x) {
    unsigned u = __float_as_uint(x);
    unsigned r = u + 0x7FFFu + ((u >> 16) & 1u);
    return (unsigned short)(r >> 16);
}
__device__ __forceinline__ float bf2f(unsigned short h) {
    return __uint_as_float(((unsigned)h) << 16);
}

// Order-preserving float->uint map: min in key space == min in float space.
__device__ __forceinline__ unsigned f2key(float f) {
    unsigned b = __float_as_uint(f);
    return (b & 0x80000000u) ? ~b : (b | 0x80000000u);
}
__device__ __forceinline__ float key2f(unsigned k) {
    return __uint_as_float((k & 0x80000000u) ? (k & 0x7FFFFFFFu) : ~k);
}

// min with DPP row_ror permute (2 VALU). CTRL: 0x120+N = row_ror:N (16-lane rows).
template <int CTRL>
__device__ __forceinline__ float dpp_ror_min(float v) {
    const int i = __float_as_int(v);
    const int p = __builtin_amdgcn_update_dpp(i, i, CTRL, 0xF, 0xF, false);
    return fminf(v, __int_as_float(p));
}

// Prep: pack scan into 512B B-fragments for 16x16x32 MFMA (split-bf16, real
// data in k0-15 only; k16-31 never stored -- A's upper quads are zero so B's
// lane 32-63 content is DON'T-CARE). Frag = 32 uint4 slots; scan point n ->
// frag g=n>>4, col c=n&15: slot g*32+c    = k0-7  [sxh,sxl,sxh,sxl, syh,syl,syh,syl]
//                          slot g*32+16+c = k8-15 [szh,szl,szh,szl, 1,1, s2h,s2l]
__global__ __launch_bounds__(BLK) void pdl_prep(const float* __restrict__ scan,
                                                uint4* __restrict__ fragbuf,
                                                unsigned* __restrict__ gmin,
                                                float* __restrict__ out,
                                                int N, int Mpad) {
    const int n = blockIdx.x * BLK + threadIdx.x;
    if (n == 0) out[0] = 0.0f;
    if (n < Mpad) gmin[n] = KEY_MAX;
    if (n >= NSLOT) return;

    unsigned short k[16];
    if (n < N) {
        const float x = scan[3 * n + 0], y = scan[3 * n + 1], z = scan[3 * n + 2];
        const float s2 = fmaf(x, x, fmaf(y, y, z * z));
        const float cx = -2.0f * x, cy = -2.0f * y, cz = -2.0f * z;
        const unsigned short xh = f2bf(cx); const unsigned short xl = f2bf(cx - bf2f(xh));
        const unsigned short yh = f2bf(cy); const unsigned short yl = f2bf(cy - bf2f(yh));
        const unsigned short zh = f2bf(cz); const unsigned short zl = f2bf(cz - bf2f(zh));
        const unsigned short wh = f2bf(s2); const unsigned short wl = f2bf(s2 - bf2f(wh));
        k[0] = xh; k[1] = xl; k[2] = xh; k[3] = xl;
        k[4] = yh; k[5] = yl; k[6] = yh; k[7] = yl;
        k[8] = zh; k[9] = zl; k[10] = zh; k[11] = zl;
        k[12] = ONE_BF; k[13] = ONE_BF;
        k[14] = wh; k[15] = wl;
    } else {  // padded slot: d2 = t2 + 1e30 -> never the min
#pragma unroll
        for (int i = 0; i < 16; ++i) k[i] = 0;
        k[12] = ONE_BF; k[13] = ONE_BF;
        k[14] = f2bf(1e30f); k[15] = 0;
    }

    const int g = n >> 4, c = n & 15;
    uint4 lo, hi;
    lo.x = (unsigned)k[0] | ((unsigned)k[1] << 16);
    lo.y = (unsigned)k[2] | ((unsigned)k[3] << 16);
    lo.z = (unsigned)k[4] | ((unsigned)k[5] << 16);
    lo.w = (unsigned)k[6] | ((unsigned)k[7] << 16);
    hi.x = (unsigned)k[8] | ((unsigned)k[9] << 16);
    hi.y = (unsigned)k[10] | ((unsigned)k[11] << 16);
    hi.z = (unsigned)k[12] | ((unsigned)k[13] << 16);
    hi.w = (unsigned)k[14] | ((unsigned)k[15] << 16);
    fragbuf[(size_t)g * 32 + c] = lo;        // consumer lanes L&31 in [0,16): k0-7
    fragbuf[(size_t)g * 32 + 16 + c] = hi;   // consumer lanes L&31 in [16,32): k8-15
}

// Main: 16x16x32 MFMA, small-state design. D/mn/zacc are 4 regs each (vs 16
// for 32x32) -> total ~65 regs -> launch_bounds(256,6), no AGPR spill
// (R14's measured sink), and grid 24x54=1296 blocks -> ~5 waves/SIMD (vs 2.5)
// to cover latency (R14's other sink: 65% idle issue). A quads 2-3 are zero
// so B needs only k0-15: every lane loads slot (lane&31) of a 512B frag.
__global__ __launch_bounds__(BLK, 6) void pdl_main(const float* __restrict__ tmpl,
                                                   const uint4* __restrict__ fragbuf,
                                                   unsigned* __restrict__ gmin,
                                                   int M) {
    const int tid = threadIdx.x;
    const int wave = tid >> 6, lane = tid & 63;
    const int quad = lane >> 4, col = lane & 15;

    // A-frags (m = template): A[m=lane&15][k=quad*8+j]  [m120-verified].
    // quad0: k0-7 = [txh,txh,txl,txl, tyh,tyh,tyl,tyl]
    // quad1: k8-15 = [tzh,tzh,tzl,tzl, t2h,t2l, 1,1] ; quads 2,3: zero.
    const int mbase = (blockIdx.y * 4 + wave) * 32;
    short8 A0, A1;
#pragma unroll
    for (int af = 0; af < 2; ++af) {
        int m = mbase + af * 16 + col;
        if (m > M - 1) m = M - 1;  // clamped dup row: same-value atomics, harmless
        const float x = tmpl[3 * m + 0], y = tmpl[3 * m + 1], z = tmpl[3 * m + 2];
        const float t2 = fmaf(x, x, fmaf(y, y, z * z));
        const unsigned short xh = f2bf(x); const unsigned short xl = f2bf(x - bf2f(xh));
        const unsigned short yh = f2bf(y); const unsigned short yl = f2bf(y - bf2f(yh));
        const unsigned short zh = f2bf(z); const unsigned short zl = f2bf(z - bf2f(zh));
        const unsigned short wh = f2bf(t2); const unsigned short wl = f2bf(t2 - bf2f(wh));
        const bool q0 = (quad == 0), q1 = (quad == 1);
        short8 a;
        a[0] = (short)(q0 ? xh : (q1 ? zh : 0));
        a[1] = (short)(q0 ? xh : (q1 ? zh : 0));
        a[2] = (short)(q0 ? xl : (q1 ? zl : 0));
        a[3] = (short)(q0 ? xl : (q1 ? zl : 0));
        a[4] = (short)(q0 ? yh : (q1 ? wh : 0));
        a[5] = (short)(q0 ? yh : (q1 ? wl : 0));
        a[6] = (short)(q0 ? yl : (q1 ? ONE_BF : 0));
        a[7] = (short)(q0 ? yl : (q1 ? ONE_BF : 0));
        if (af == 0) A0 = a; else A1 = a;
    }

    floatx4 mn0, mn1, zacc;
#pragma unroll
    for (int r = 0; r < 4; ++r) { mn0[r] = 3e30f; mn1[r] = 3e30f; zacc[r] = 0.0f; }

    // All 64 lanes address slot (lane&31): upper half re-reads the same 512B
    // (same cachelines); its B content lands in k16-31 which A zeros kill.
    const uint4* fb = fragbuf + (size_t)(blockIdx.x * FPS) * 32 + (lane & 31);

    union U { uint4 u; short8 s; };
    // 4-deep prefetch (~280cyc coverage > ~200cyc L2 latency). Over-reads 8
    // frags past split end; fragbuf padded.
    uint4 p0 = fb[0 * 32], p1 = fb[1 * 32], p2 = fb[2 * 32], p3 = fb[3 * 32];
#pragma unroll 1
    for (int f = 0; f < FPS; f += 4) {
        U c0, c1, c2, c3;
        c0.u = p0; c1.u = p1; c2.u = p2; c3.u = p3;
        p0 = fb[(size_t)(f + 4) * 32];
        p1 = fb[(size_t)(f + 5) * 32];
        p2 = fb[(size_t)(f + 6) * 32];
        p3 = fb[(size_t)(f + 7) * 32];
        const floatx4 d00 = __builtin_amdgcn_mfma_f32_16x16x32_bf16(A0, c0.s, zacc, 0, 0, 0);
        const floatx4 d10 = __builtin_amdgcn_mfma_f32_16x16x32_bf16(A1, c0.s, zacc, 0, 0, 0);
        const floatx4 d01 = __builtin_amdgcn_mfma_f32_16x16x32_bf16(A0, c1.s, zacc, 0, 0, 0);
        const floatx4 d11 = __builtin_amdgcn_mfma_f32_16x16x32_bf16(A1, c1.s, zacc, 0, 0, 0);
#pragma unroll
        for (int r = 0; r < 4; ++r) {
            mn0[r] = fminf(fminf(d00[r], d01[r]), mn0[r]);  // -> v_min3_f32
            mn1[r] = fminf(fminf(d10[r], d11[r]), mn1[r]);
        }
        const floatx4 d02 = __builtin_amdgcn_mfma_f32_16x16x32_bf16(A0, c2.s, zacc, 0, 0, 0);
        const floatx4 d12 = __builtin_amdgcn_mfma_f32_16x16x32_bf16(A1, c2.s, zacc, 0, 0, 0);
        const floatx4 d03 = __builtin_amdgcn_mfma_f32_16x16x32_bf16(A0, c3.s, zacc, 0, 0, 0);
        const floatx4 d13 = __builtin_amdgcn_mfma_f32_16x16x32_bf16(A1, c3.s, zacc, 0, 0, 0);
#pragma unroll
        for (int r = 0; r < 4; ++r) {
            mn0[r] = fminf(fminf(d02[r], d03[r]), mn0[r]);
            mn1[r] = fminf(fminf(d12[r], d13[r]), mn1[r]);
        }
    }

    // Epilogue: C/D layout col=lane&15, row=quad*4+r  [m89-verified]. Min over
    // the 16 cols = DPP row_ror chain within each 16-lane row; no ds_swizzle.
#pragma unroll
    for (int af = 0; af < 2; ++af) {
#pragma unroll
        for (int r = 0; r < 4; ++r) {
            float v = (af == 0) ? mn0[r] : mn1[r];
            v = dpp_ror_min<0x128>(v);  // row_ror:8
            v = dpp_ror_min<0x124>(v);  // row_ror:4
            v = dpp_ror_min<0x122>(v);  // row_ror:2
            v = dpp_ror_min<0x121>(v);  // row_ror:1
            if (col == 0) {
                const int m = mbase + af * 16 + quad * 4 + r;
                atomicMin(&gmin[m], f2key(v));
            }
        }
    }
}

// Unmap, threshold, block-reduce, atomicAdd.
__global__ __launch_bounds__(BLK) void pdl_final(const unsigned* __restrict__ gmin,
                                                 float* __restrict__ out, int M) {
    const int m = blockIdx.x * BLK + threadIdx.x;
    float s = 0.0f;
    if (m < M) {
        const float v = key2f(gmin[m]);
        if (v < THRESH) s = v;
    }
#pragma unroll
    for (int off = 32; off > 0; off >>= 1) s += __shfl_down(s, off, 64);

    __shared__ float ls[BLK / 64];
    const int lane = threadIdx.x & 63;
    const int w = threadIdx.x >> 6;
    if (lane == 0) ls[w] = s;
    __syncthreads();
    if (threadIdx.x == 0) {
        float t = 0.0f;
#pragma unroll
        for (int i = 0; i < BLK / 64; ++i) t += ls[i];
        atomicAdd(out, t);
    }
}

extern "C" void kernel_launch(void* const* d_in, const int* in_sizes, int n_in,
                              void* d_out, int out_size, void* d_ws, size_t ws_size,
                              hipStream_t stream) {
    const float* scan = (const float*)d_in[0];   // [N,3] fp32
    const float* tmpl = (const float*)d_in[1];   // [M,3] fp32
    float* out = (float*)d_out;                  // scalar fp32

    const int N = in_sizes[0] / 3;               // 50000
    const int M = in_sizes[1] / 3;               // 6890

    const int tGroups = (M + 127) / 128;         // 54 blocks of 128 templates
    const int Mpad = tGroups * 128;              // 6912

    // ws: gmin [0, 64KB) ; fragbuf at 64KB: (FRTOT+8) frags x 512B ~ 1.67 MB
    unsigned* gmin = (unsigned*)d_ws;
    uint4* fragbuf = (uint4*)((char*)d_ws + 65536);

    pdl_prep<<<(NSLOT + BLK - 1) / BLK, BLK, 0, stream>>>(scan, fragbuf, gmin,
                                                          out, N, Mpad);

    dim3 grid(SPLITS, tGroups);
    pdl_main<<<grid, BLK, 0, stream>>>(tmpl, fragbuf, gmin, M);

    pdl_final<<<(M + BLK - 1) / BLK, BLK, 0, stream>>>(gmin, out, M);
}